// Round 8
// baseline (278.511 us; speedup 1.0000x reference)
//
#include <hip/hip_runtime.h>
#include <stdint.h>

// Problem constants
#define BATCH 2
#define TDIM 2048
#define EDIM 2048
#define NH 16
#define HD 128
#define E3 6144
#define MROWS 4096  // BATCH*TDIM
#define QKS 4096    // row stride of compacted Q|K buffer

typedef short v8bf __attribute__((ext_vector_type(8)));   // 8 bf16 bit patterns (4 VGPRs)
typedef float v4f  __attribute__((ext_vector_type(4)));

typedef __attribute__((address_space(3))) uint8_t lds_u8;
typedef __attribute__((address_space(1))) uint8_t glb_u8;

__device__ __forceinline__ void gload16(const void* g, void* l) {
    __builtin_amdgcn_global_load_lds((const glb_u8*)g, (lds_u8*)l, 16, 0, 0);
}

__device__ __forceinline__ ushort f2bf(float f) {
    uint32_t u = __float_as_uint(f);
    return (ushort)((u + 0x7fffu + ((u >> 16) & 1u)) >> 16);  // RNE
}

// ---------------- fused preprocessing: tcvt(w_qkv) + tcvt(w_out) + cvtx(x) ----------------
__device__ __forceinline__ void tcvt_body(const float* __restrict__ in, ushort* __restrict__ out,
                                          int R, int C, int tcb, int trb, int tid) {
    __shared__ float t[32][33];
    const int tc = tcb * 32, tr = trb * 32;
    const int row = tid >> 3, c4 = (tid & 7) * 4;
    const float4 v = *reinterpret_cast<const float4*>(in + (size_t)(tr + row) * C + tc + c4);
    t[row][c4] = v.x; t[row][c4 + 1] = v.y; t[row][c4 + 2] = v.z; t[row][c4 + 3] = v.w;
    __syncthreads();
    const int oc = tid >> 3, r4 = (tid & 7) * 4;
    ushort4 o = make_ushort4(f2bf(t[r4][oc]), f2bf(t[r4 + 1][oc]),
                             f2bf(t[r4 + 2][oc]), f2bf(t[r4 + 3][oc]));
    *reinterpret_cast<ushort4*>(out + (size_t)(tc + oc) * R + tr + r4) = o;
}

#define NB_T1 12288   // (6144/32)*(2048/32)
#define NB_T2 4096    // (2048/32)*(2048/32)
#define NB_CV 2048

__global__ void prep_kernel(const float* __restrict__ x, const float* __restrict__ w_qkv,
                            const float* __restrict__ w_out, ushort* __restrict__ xb,
                            ushort* __restrict__ wqkvT, ushort* __restrict__ woutT) {
    const int bid = blockIdx.x;
    const int tid = threadIdx.x;
    if (bid < NB_T1) {
        tcvt_body(w_qkv, wqkvT, EDIM, E3, bid % (E3 / 32), bid / (E3 / 32), tid);
    } else if (bid < NB_T1 + NB_T2) {
        const int b2 = bid - NB_T1;
        tcvt_body(w_out, woutT, EDIM, EDIM, b2 % (EDIM / 32), b2 / (EDIM / 32), tid);
    } else {
        const int b3 = bid - NB_T1 - NB_T2;
        int i = (b3 * 256 + tid) * 4;
        const int stride = NB_CV * 256 * 4;
        const int n = MROWS * EDIM;
        for (; i < n; i += stride) {
            const float4 v = *reinterpret_cast<const float4*>(x + i);
            ushort4 o = make_ushort4(f2bf(v.x), f2bf(v.y), f2bf(v.z), f2bf(v.w));
            *reinterpret_cast<ushort4*>(xb + i) = o;
        }
    }
}

// ---------------- GEMM1: 256x256, BK=64, 8 waves, 8-phase counted pipeline (m201 port) ----
// qkv = xb[M][K] * wqkvT[N][K]^T, split: cols<4096 -> qk (stride QKS); cols>=4096 -> vt transposed.
// M%256==0, N%256==0, K%128==0 (even NT), nwg%8==0.
__global__ __launch_bounds__(512, 1) void gemm256q_kernel(const ushort* __restrict__ A,
                                                          const ushort* __restrict__ Bt,
                                                          ushort* __restrict__ qkout,
                                                          ushort* __restrict__ vtout,
                                                          int Mdim, int Ndim, int Kdim) {
    __shared__ __align__(16) ushort AL[2][2][128 * 64];   // [buf][half][row][64]
    __shared__ __align__(16) ushort BL[2][2][128 * 64];   // 128 KiB total
    const int tid = threadIdx.x;
    const int lane = tid & 63;
    const int wv = tid >> 6;               // 0..7
    const int l4 = lane >> 4, l16 = lane & 15;
    const int wr = wv >> 2, wc = wv & 3;   // 2M x 4N wave grid; wave tile 128x64
    const int nbn = Ndim >> 8;
    const int nwg = (Mdim >> 8) * nbn;
    int bid = blockIdx.x;
    bid = (bid & 7) * (nwg >> 3) + (bid >> 3);   // XCD swizzle (nwg % 8 == 0)
    const int bm = bid / nbn, bn = bid % nbn;

    const ushort* Abase = A + (size_t)(bm * 256) * Kdim;
    const ushort* Bbase = Bt + (size_t)(bn * 256) * Kdim;
    const int NT = Kdim >> 6;

    // --- staging: half-tile (128 rows x 64 cols = 16KB) = 2 gloads/thread, linear LDS dest,
    //     pre-swizzled global source (inverse of read-side XOR) ---
#define STG_HALF(LDST, GB, H, T)                                                              \
    do {                                                                                      \
        { const int s = wv * 64 + lane; const int row = s >> 3;                               \
          const int kc = (s & 7) ^ (row & 7);                                                 \
          gload16(GB + (size_t)((H) * 128 + row) * Kdim + (T) * 64 + kc * 8,                  \
                  &LDST[(wv * 64) * 8]); }                                                    \
        { const int s = 512 + wv * 64 + lane; const int row = s >> 3;                         \
          const int kc = (s & 7) ^ (row & 7);                                                 \
          gload16(GB + (size_t)((H) * 128 + row) * Kdim + (T) * 64 + kc * 8,                  \
                  &LDST[(512 + wv * 64) * 8]); }                                              \
    } while (0)
#define STG_A(BUF, T) do { STG_HALF(AL[BUF][0], Abase, 0, T); STG_HALF(AL[BUF][1], Abase, 1, T); } while (0)
#define STG_B(BUF, T) do { STG_HALF(BL[BUF][0], Bbase, 0, T); STG_HALF(BL[BUF][1], Bbase, 1, T); } while (0)

#define LOAD_AF(BUF, MQ)                                                                      \
    _Pragma("unroll") for (int m = 0; m < 4; ++m)                                             \
    _Pragma("unroll") for (int kk = 0; kk < 2; ++kk) {                                        \
        const int rl = (MQ) * 64 + m * 16 + l16;                                              \
        const int slot = (kk * 4 + l4) ^ (l16 & 7);                                           \
        af[m][kk] = *reinterpret_cast<const v8bf*>(&AL[BUF][wr][rl * 64 + slot * 8]);         \
    }
#define LOAD_BF(BUF, NQ)                                                                      \
    _Pragma("unroll") for (int n = 0; n < 2; ++n)                                             \
    _Pragma("unroll") for (int kk = 0; kk < 2; ++kk) {                                        \
        const int rl = (wc & 1) * 64 + (NQ) * 32 + n * 16 + l16;                              \
        const int slot = (kk * 4 + l4) ^ (l16 & 7);                                           \
        bf[n][kk] = *reinterpret_cast<const v8bf*>(&BL[BUF][wc >> 1][rl * 64 + slot * 8]);    \
    }
#define MFMA16(MQ, NQ)                                                                        \
    __builtin_amdgcn_s_setprio(1);                                                            \
    _Pragma("unroll") for (int kk = 0; kk < 2; ++kk)                                          \
    _Pragma("unroll") for (int m = 0; m < 4; ++m)                                             \
    _Pragma("unroll") for (int n = 0; n < 2; ++n)                                             \
        acc[MQ][m][NQ][n] = __builtin_amdgcn_mfma_f32_16x16x32_bf16(                          \
            af[m][kk], bf[n][kk], acc[MQ][m][NQ][n], 0, 0, 0);                                \
    __builtin_amdgcn_s_setprio(0);
#define BARS() __builtin_amdgcn_s_barrier(); __builtin_amdgcn_sched_barrier(0)
#define WAITLGKM() asm volatile("s_waitcnt lgkmcnt(0)" ::: "memory"); __builtin_amdgcn_sched_barrier(0)
#define WAITVM0() asm volatile("s_waitcnt vmcnt(0)" ::: "memory")

    v4f acc[2][4][2][2] = {};   // [mq][m][nq][n]

    // Prologue: tile 0 -> buf0
    STG_A(0, 0); STG_B(0, 0);
    WAITVM0();
    BARS();

    for (int T = 0; T < NT; T += 2) {
        v8bf af[4][2], bf[2][2];
        // ---- Ph1: tile T (buf0) quadrant (0,0); issue A of tile T+1 -> buf1 ----
        LOAD_AF(0, 0) LOAD_BF(0, 0)
        STG_A(1, T + 1);
        BARS(); WAITLGKM();
        MFMA16(0, 0)
        BARS();
        // ---- Ph2: (0,1); issue B of tile T+1 ----
        LOAD_BF(0, 1)
        STG_B(1, T + 1);
        BARS(); WAITLGKM();
        MFMA16(0, 1)
        BARS();
        // ---- Ph3: (1,0) ----
        LOAD_AF(0, 1) LOAD_BF(0, 0)
        BARS(); WAITLGKM();
        MFMA16(1, 0)
        BARS();
        // ---- Ph4: (1,1); drain -> tile T+1 resident ----
        LOAD_BF(0, 1)
        BARS(); WAITLGKM();
        MFMA16(1, 1)
        WAITVM0();
        BARS();
        // ---- Ph5: tile T+1 (buf1) quadrant (0,0); issue A of tile T+2 -> buf0 ----
        LOAD_AF(1, 0) LOAD_BF(1, 0)
        if (T + 2 < NT) STG_A(0, T + 2);
        BARS(); WAITLGKM();
        MFMA16(0, 0)
        BARS();
        // ---- Ph6: (0,1); issue B of tile T+2 ----
        LOAD_BF(1, 1)
        if (T + 2 < NT) STG_B(0, T + 2);
        BARS(); WAITLGKM();
        MFMA16(0, 1)
        BARS();
        // ---- Ph7: (1,0) ----
        LOAD_AF(1, 1) LOAD_BF(1, 0)
        BARS(); WAITLGKM();
        MFMA16(1, 0)
        BARS();
        // ---- Ph8: (1,1); drain -> tile T+2 resident ----
        LOAD_BF(1, 1)
        BARS(); WAITLGKM();
        MFMA16(1, 1)
        WAITVM0();
        BARS();
    }
#undef STG_HALF
#undef STG_A
#undef STG_B
#undef LOAD_AF
#undef LOAD_BF
#undef MFMA16
#undef BARS
#undef WAITLGKM
#undef WAITVM0

    // Epilogue: split QKV. C/D layout: col = lane&15, row = (lane>>4)*4 + j.
    const bool isV = (bn >= 16);   // cols bn*256 >= 4096 -> V (block-uniform)
#pragma unroll
    for (int mq = 0; mq < 2; ++mq)
#pragma unroll
        for (int m = 0; m < 4; ++m) {
            const int r = bm * 256 + wr * 128 + mq * 64 + m * 16 + l4 * 4;
#pragma unroll
            for (int nq = 0; nq < 2; ++nq)
#pragma unroll
                for (int n = 0; n < 2; ++n) {
                    const int c = bn * 256 + wc * 64 + nq * 32 + n * 16 + l16;
                    if (isV) {
                        const int cv = c - 4096;
                        const int h = cv >> 7, d = cv & 127;
                        const int b = r >> 11, t0 = r & 2047;
                        ushort* vp = vtout + (size_t)(((b << 4) + h) * 128 + d) * TDIM + t0;
#pragma unroll
                        for (int j = 0; j < 4; ++j)
                            vp[j] = f2bf(acc[mq][m][nq][n][j]);
                    } else {
#pragma unroll
                        for (int j = 0; j < 4; ++j)
                            qkout[(size_t)(r + j) * QKS + c] = f2bf(acc[mq][m][nq][n][j]);
                    }
                }
        }
}

// ---------------- bf16 GEMM (128x128, m97-structure) -- GEMM2 (f32 out + bias) ----------------
template <int OUTF32>
__global__ void gemm_kernel(const ushort* __restrict__ A, const ushort* __restrict__ Bt,
                            void* __restrict__ Cv, const float* __restrict__ bias,
                            int Mdim, int Ndim, int Kdim) {
    __shared__ __align__(16) ushort As[128 * 64];
    __shared__ __align__(16) ushort Bs[128 * 64];
    const int tid = threadIdx.x;
    const int lane = tid & 63;
    const int wv = tid >> 6;
    const int l4 = lane >> 4, l16 = lane & 15;
    const int nbn = Ndim >> 7;
    const int nwg = (Mdim >> 7) * nbn;
    int bid = blockIdx.x;
    bid = (bid & 7) * (nwg >> 3) + (bid >> 3);   // XCD swizzle (nwg % 8 == 0)
    const int bm = bid / nbn, bn = bid % nbn;
    const int wr = wv >> 1, wc = wv & 1;

    const ushort* Abase = A + (size_t)(bm * 128) * Kdim;
    const ushort* Bbase = Bt + (size_t)(bn * 128) * Kdim;

    v4f acc[4][4] = {};

    for (int k0 = 0; k0 < Kdim; k0 += 64) {
#pragma unroll
        for (int i = 0; i < 4; ++i) {
            const int c = i * 256 + tid;
            const int row = c >> 3;
            const int kc = (c & 7) ^ (row & 7);    // pre-swizzled global source
            gload16(Abase + (size_t)row * Kdim + k0 + kc * 8, &As[(i * 256 + wv * 64) * 8]);
        }
#pragma unroll
        for (int i = 0; i < 4; ++i) {
            const int c = i * 256 + tid;
            const int row = c >> 3;
            const int kc = (c & 7) ^ (row & 7);
            gload16(Bbase + (size_t)row * Kdim + k0 + kc * 8, &Bs[(i * 256 + wv * 64) * 8]);
        }
        __syncthreads();
#pragma unroll
        for (int kk = 0; kk < 2; ++kk) {
            v8bf af[4], bfr[4];
#pragma unroll
            for (int m = 0; m < 4; ++m) {
                const int r = wr * 64 + m * 16 + l16;
                const int slot = (kk * 4 + l4) ^ (r & 7);
                af[m] = *reinterpret_cast<const v8bf*>(&As[r * 64 + slot * 8]);
            }
#pragma unroll
            for (int n = 0; n < 4; ++n) {
                const int r = wc * 64 + n * 16 + l16;
                const int slot = (kk * 4 + l4) ^ (r & 7);
                bfr[n] = *reinterpret_cast<const v8bf*>(&Bs[r * 64 + slot * 8]);
            }
#pragma unroll
            for (int m = 0; m < 4; ++m)
#pragma unroll
                for (int n = 0; n < 4; ++n)
                    acc[m][n] = __builtin_amdgcn_mfma_f32_16x16x32_bf16(af[m], bfr[n], acc[m][n], 0, 0, 0);
        }
        __syncthreads();
    }

    const int r0 = bm * 128 + wr * 64 + l4 * 4;
    const int c0 = bn * 128 + wc * 64 + l16;
    if (OUTF32) {
        float* Cf = (float*)Cv;
#pragma unroll
        for (int n = 0; n < 4; ++n) {
            const float bv = bias[c0 + n * 16];
#pragma unroll
            for (int m = 0; m < 4; ++m)
#pragma unroll
                for (int j = 0; j < 4; ++j)
                    Cf[(size_t)(r0 + m * 16 + j) * Ndim + c0 + n * 16] = acc[m][n][j] + bv;
        }
    } else {
        ushort* Cb = (ushort*)Cv;
#pragma unroll
        for (int n = 0; n < 4; ++n)
#pragma unroll
            for (int m = 0; m < 4; ++m)
#pragma unroll
                for (int j = 0; j < 4; ++j)
                    Cb[(size_t)(r0 + m * 16 + j) * Ndim + c0 + n * 16] = f2bf(acc[m][n][j]);
    }
}

// ---------------- Flash attention v3 (causal, balanced split-row binning) ----------------
// qk [4096][4096] bf16 (Q cols 0..2047, K cols 2048..4095); vt [bh][128][2048]; ao [4096][2048]
__global__ __launch_bounds__(256, 2) void flash_kernel(const ushort* __restrict__ qk,
                                                       const ushort* __restrict__ vt,
                                                       ushort* __restrict__ ao) {
    __shared__ __align__(16) ushort Kl[2][64 * 128];   // [kv][d], 16B d-chunks XOR-swizzled
    __shared__ __align__(16) ushort Vl[2][128 * 64];   // [d][kv], 16B kv-chunks XOR-swizzled
    __shared__ __align__(16) ushort Pl[128 * 64];      // [slot][kv], XOR-swizzled

    const int xi = blockIdx.x;
    const int ti = (xi & 1) ? (xi >> 1) : (15 - (xi >> 1));  // heavy/light interleave
    const int h = blockIdx.y;
    const int b = blockIdx.z;
    const int tid = threadIdx.x;
    const int lane = tid & 63;
    const int wv = tid >> 6;
    const int l4 = lane >> 4, l16 = lane & 15;

    const int rbs[2]  = {ti * 64 + wv * 16, TDIM - 64 * (ti + 1) + wv * 16};  // block-local T rows
    const int diag[2] = {ti, 31 - ti};
    const int nkt = 32 - ti;

    // Q fragments, scale folded in (A-layout: row = lane&15, k = (lane>>4)*8 + ...)
    v8bf qf[2][4];
#pragma unroll
    for (int mg = 0; mg < 2; ++mg) {
        const ushort* qp = qk + (size_t)(b * TDIM + rbs[mg] + l16) * QKS + h * HD + l4 * 8;
#pragma unroll
        for (int d0 = 0; d0 < 4; ++d0) {
            v8bf r = *reinterpret_cast<const v8bf*>(qp + d0 * 32);
            v8bf o;
#pragma unroll
            for (int e = 0; e < 8; ++e) {
                const float f = __uint_as_float(((uint32_t)(ushort)r[e]) << 16) * 0.08838834764831845f;
                o[e] = (short)f2bf(f);
            }
            qf[mg][d0] = o;
        }
    }

    float mrun[2][4], lrun[2][4];
#pragma unroll
    for (int mg = 0; mg < 2; ++mg)
#pragma unroll
        for (int j = 0; j < 4; ++j) { mrun[mg][j] = -1e30f; lrun[mg][j] = 0.0f; }
    v4f oacc[2][8] = {};

    const ushort* kbase = qk + (size_t)(b * TDIM) * QKS + EDIM + h * HD;
    const ushort* vbase = vt + (size_t)((b * 16 + h) * HD) * TDIM;

#define STAGE(BUF, KT)                                                                        \
    do {                                                                                      \
        _Pragma("unroll") for (int i = 0; i < 4; ++i) {                                       \
            const int c = i * 256 + tid;                                                      \
            const int row = c >> 4;                                                           \
            const int dc = (c & 15) ^ (row & 7);                                              \
            gload16(kbase + (size_t)((KT) * 64 + row) * QKS + dc * 8,                         \
                    &Kl[BUF][(i * 256 + wv * 64) * 8]);                                       \
        }                                                                                     \
        _Pragma("unroll") for (int i = 0; i < 4; ++i) {                                       \
            const int c = i * 256 + tid;                                                      \
            const int row = c >> 3;                                                           \
            const int jc = (c & 7) ^ (row & 7);                                               \
            gload16(vbase + (size_t)row * TDIM + (KT) * 64 + jc * 8,                          \
                    &Vl[BUF][(i * 256 + wv * 64) * 8]);                                       \
        }                                                                                     \
    } while (0)

    STAGE(0, 0);
    __syncthreads();
    int cur = 0;

    for (int kt = 0; kt < nkt; ++kt) {
        if (kt + 1 < nkt) STAGE(cur ^ 1, kt + 1);   // prefetch overlaps compute

        const bool act0 = (kt <= diag[0]);          // mg0 active until its diagonal
        const ushort* Kb = &Kl[cur][0];
        const ushort* Vb = &Vl[cur][0];

        // ---- S = Q @ K^T ----
        v4f s[2][4] = {};
#pragma unroll
        for (int d0 = 0; d0 < 4; ++d0) {
            v8bf kf[4];
#pragma unroll
            for (int kvn = 0; kvn < 4; ++kvn) {
                const int r = kvn * 16 + l16;
                const int slot = (d0 * 4 + l4) ^ (r & 7);
                kf[kvn] = *reinterpret_cast<const v8bf*>(&Kb[r * 128 + slot * 8]);
            }
#pragma unroll
            for (int kvn = 0; kvn < 4; ++kvn) {
                if (act0)
                    s[0][kvn] = __builtin_amdgcn_mfma_f32_16x16x32_bf16(qf[0][d0], kf[kvn], s[0][kvn], 0, 0, 0);
                s[1][kvn] = __builtin_amdgcn_mfma_f32_16x16x32_bf16(qf[1][d0], kf[kvn], s[1][kvn], 0, 0, 0);
            }
        }

        // ---- per-group softmax + P write ----
#pragma unroll
        for (int mg = 0; mg < 2; ++mg) {
            if (mg == 0 && !act0) continue;

            float sv[4][4];
#pragma unroll
            for (int kvn = 0; kvn < 4; ++kvn)
#pragma unroll
                for (int j = 0; j < 4; ++j)
                    sv[kvn][j] = s[mg][kvn][j];

            if (kt == diag[mg]) {  // diagonal tile mask (block-local T coords)
                const int rg = rbs[mg] + l4 * 4;
#pragma unroll
                for (int kvn = 0; kvn < 4; ++kvn) {
                    const int cg = kt * 64 + kvn * 16 + l16;
#pragma unroll
                    for (int j = 0; j < 4; ++j)
                        if (cg > rg + j) sv[kvn][j] = -__builtin_inff();
                }
            }

            // row max (row spans the 16-lane group)
            float pm[4], dmax = -1e30f;
#pragma unroll
            for (int j = 0; j < 4; ++j) {
                float m0 = fmaxf(fmaxf(sv[0][j], sv[1][j]), fmaxf(sv[2][j], sv[3][j]));
                m0 = fmaxf(m0, __shfl_xor(m0, 1));
                m0 = fmaxf(m0, __shfl_xor(m0, 2));
                m0 = fmaxf(m0, __shfl_xor(m0, 4));
                m0 = fmaxf(m0, __shfl_xor(m0, 8));
                pm[j] = m0;
                dmax = fmaxf(dmax, m0 - mrun[mg][j]);
            }
            if (!__all(dmax <= 8.0f)) {   // T13 defer-max: rescale only when needed
                float corr[4];
#pragma unroll
                for (int j = 0; j < 4; ++j) {
                    const float mn = fmaxf(mrun[mg][j], pm[j]);
                    corr[j] = __expf(mrun[mg][j] - mn);
                    mrun[mg][j] = mn;
                    lrun[mg][j] *= corr[j];
                }
#pragma unroll
                for (int n = 0; n < 8; ++n)
#pragma unroll
                    for (int j = 0; j < 4; ++j)
                        oacc[mg][n][j] *= corr[j];
            }

            float p[4][4];
#pragma unroll
            for (int kvn = 0; kvn < 4; ++kvn)
#pragma unroll
                for (int j = 0; j < 4; ++j)
                    p[kvn][j] = __expf(sv[kvn][j] - mrun[mg][j]);
#pragma unroll
            for (int j = 0; j < 4; ++j)
                lrun[mg][j] += p[0][j] + p[1][j] + p[2][j] + p[3][j];

            // P -> LDS (swizzled), same-wave slots only
            const int row = wv * 32 + mg * 16 + l4 * 4;
#pragma unroll
            for (int kvn = 0; kvn < 4; ++kvn) {
                const int cc = kvn * 2 + (l16 >> 3);
#pragma unroll
                for (int j = 0; j < 4; ++j) {
                    const int r = row + j;
                    Pl[r * 64 + ((cc ^ (r & 7)) * 8) + (l16 & 7)] = f2bf(p[kvn][j]);
                }
            }
        }

        // ---- O += P @ V ----
#pragma unroll
        for (int kk = 0; kk < 2; ++kk) {
            v8bf pf[2];
#pragma unroll
            for (int mg = 0; mg < 2; ++mg) {
                if (mg == 0 && !act0) continue;
                const int r = wv * 32 + mg * 16 + l16;
                const int slot = (kk * 4 + l4) ^ (r & 7);
                pf[mg] = *reinterpret_cast<const v8bf*>(&Pl[r * 64 + slot * 8]);
            }
#pragma unroll
            for (int n = 0; n < 8; ++n) {
                const int dr = n * 16 + l16;
                const int slot = (kk * 4 + l4) ^ (dr & 7);
                v8bf vf = *reinterpret_cast<const v8bf*>(&Vb[dr * 64 + slot * 8]);
                if (act0)
                    oacc[0][n] = __builtin_amdgcn_mfma_f32_16x16x32_bf16(pf[0], vf, oacc[0][n], 0, 0, 0);
                oacc[1][n] = __builtin_amdgcn_mfma_f32_16x16x32_bf16(pf[1], vf, oacc[1][n], 0, 0, 0);
            }
        }
        __syncthreads();
        cur ^= 1;
    }
#undef STAGE

    // ---- epilogue: finish l reduction, normalize, store ----
#pragma unroll
    for (int mg = 0; mg < 2; ++mg) {
        float inv[4];
#pragma unroll
        for (int j = 0; j < 4; ++j) {
            float l = lrun[mg][j];
            l += __shfl_xor(l, 1);
            l += __shfl_xor(l, 2);
            l += __shfl_xor(l, 4);
            l += __shfl_xor(l, 8);
            inv[j] = 1.0f / l;
        }
        ushort* aop = ao + (size_t)(b * TDIM + rbs[mg] + l4 * 4) * EDIM + h * HD + l16;
#pragma unroll
        for (int n = 0; n < 8; ++n)
#pragma unroll
            for (int j = 0; j < 4; ++j)
                aop[(size_t)j * EDIM + n * 16] = f2bf(oacc[mg][n][j] * inv[j]);
    }
}

// ---------------- launcher ----------------
extern "C" void kernel_launch(void* const* d_in, const int* in_sizes, int n_in,
                              void* d_out, int out_size, void* d_ws, size_t ws_size,
                              hipStream_t stream) {
    (void)in_sizes; (void)n_in; (void)out_size; (void)ws_size;
    const float* x     = (const float*)d_in[0];
    const float* w_qkv = (const float*)d_in[1];
    const float* w_out = (const float*)d_in[2];
    const float* b_out = (const float*)d_in[3];

    uint8_t* ws = (uint8_t*)d_ws;
    // layout (bytes):
    //   qk    @ 0         : 4096*4096*2 = 33554432   (Q|K, row stride 4096)
    //   vt    @ 33554432  : 32*128*2048*2 = 16777216 (V transposed per head)
    //   woutT @ 50331648  : 2048*2048*2 =  8388608
    //   xb    @ 58720256  : 4096*2048*2 = 16777216
    //   wqkvT @ 75497472  : 6144*2048*2 = 25165824   (aliased by ao after GEMM1)
    ushort* qk    = (ushort*)(ws);
    ushort* vtb   = (ushort*)(ws + 33554432u);
    ushort* woutT = (ushort*)(ws + 50331648u);
    ushort* xb    = (ushort*)(ws + 58720256u);
    ushort* wqkvT = (ushort*)(ws + 75497472u);
    ushort* ao    = wqkvT;  // reuse after GEMM1 consumed wqkvT

    prep_kernel<<<NB_T1 + NB_T2 + NB_CV, 256, 0, stream>>>(x, w_qkv, w_out, xb, wqkvT, woutT);

    gemm256q_kernel<<<(MROWS / 256) * (E3 / 256), 512, 0, stream>>>(
        xb, wqkvT, qk, vtb, MROWS, E3, EDIM);

    flash_kernel<<<dim3(16, NH, BATCH), 256, 0, stream>>>(qk, vtb, ao);

    gemm_kernel<1><<<(MROWS / 128) * (EDIM / 128), 256, 0, stream>>>(
        ao, woutT, d_out, b_out, MROWS, EDIM, EDIM);
}